// Round 6
// baseline (9463.672 us; speedup 1.0000x reference)
//
#include <hip/hip_runtime.h>
#include <hip/hip_fp16.h>

typedef _Float16 f16;
typedef unsigned int u32;
typedef unsigned short u16;
typedef unsigned long long u64;
typedef _Float16 f16x8 __attribute__((ext_vector_type(8)));
typedef float f32x4 __attribute__((ext_vector_type(4)));
typedef float f32x16 __attribute__((ext_vector_type(16)));

#define SEQ   512
#define HID   512
#define NSK   1024
#define INDIM 2048
#define G4    2048
#define NWG   64
#define HSTEP 32768      // f16 per timestep, layout [b][u]

// ---- workspace layout (bytes) ----
#define H1_OFF    0ull
#define H2_OFF    33554432ull
#define WHH0_OFF  67108864ull
#define WIH1_OFF  69206016ull
#define WHH1_OFF  71303168ull
#define FCW_OFF   73400320ull
#define B0_OFF    74448896ull
#define B1_OFF    74457088ull
#define W0P_OFF   74465280ull   // 8 MB: [2048 col][64 wg][32 j]  f16, j = gate*8 + unit
#define FLG_OFF   82853888ull   // 256 per-wave flags, 64B apart (u32 stride 16)

__device__ __forceinline__ float sigmoidf_(float x) {
    return 1.0f / (1.0f + __expf(-x));
}
__device__ __forceinline__ float tanhf_(float x) {
    return 2.0f * sigmoidf_(2.0f * x) - 1.0f;
}

__device__ __forceinline__ float dot2_(u32 a, u32 b, float c) {
    typedef _Float16 h2t __attribute__((ext_vector_type(2)));
    h2t ha = __builtin_bit_cast(h2t, a);
    h2t hb = __builtin_bit_cast(h2t, b);
#if __has_builtin(__builtin_amdgcn_fdot2)
    return __builtin_amdgcn_fdot2(ha, hb, c, false);
#else
    return c + (float)ha[0] * (float)hb[0] + (float)ha[1] * (float)hb[1];
#endif
}

// ---- prep: f16 weight copies + fused biases + flag zeroing ----
__global__ __launch_bounds__(256) void prep_kernel(
    const float* __restrict__ Whh0, const float* __restrict__ Wih1,
    const float* __restrict__ Whh1, const float* __restrict__ fcW,
    const float* __restrict__ bih0, const float* __restrict__ bhh0,
    const float* __restrict__ bih1, const float* __restrict__ bhh1,
    f16* __restrict__ whh0h, f16* __restrict__ wih1h,
    f16* __restrict__ whh1h, f16* __restrict__ fcwh,
    float* __restrict__ b0, float* __restrict__ b1, u32* __restrict__ flags)
{
    int i = blockIdx.x * 256 + threadIdx.x;
    if (i < G4 * HID) {
        whh0h[i] = (f16)Whh0[i];
        wih1h[i] = (f16)Wih1[i];
        whh1h[i] = (f16)Whh1[i];
    }
    if (i < NSK * HID) fcwh[i] = (f16)fcW[i];
    if (i < G4) { b0[i] = bih0[i] + bhh0[i]; b1[i] = bih1[i] + bhh1[i]; }
    if (i < 4096) flags[i] = 0;
}

// ---- W0P build: W0P[c][wg][j] = Wih0[r][c], r = (j>>3)*512 + wg*8 + (j&7) ----
__global__ __launch_bounds__(256) void w0p_kernel(
    const float* __restrict__ Wih0, f16* __restrict__ w0p)
{
    __shared__ float tl[64][65];
    const int tid = threadIdx.x;
    const int ct = blockIdx.x & 31, rt = blockIdx.x >> 5;
    const int r0 = rt * 64, c0 = ct * 64;
#pragma unroll 4
    for (int i = 0; i < 16; ++i) {
        int rr = i * 4 + (tid >> 6);
        int cc = tid & 63;
        tl[rr][cc] = Wih0[(size_t)(r0 + rr) * INDIM + c0 + cc];
    }
    __syncthreads();
    const int jh = r0 >> 9;            // gate (const in tile)
    const int wg0 = (r0 & 511) >> 3;   // first wg chunk
    for (int task = tid; task < 512; task += 256) {
        int c = task >> 3, wgl = task & 7;
        f16 tmp[8];
#pragma unroll
        for (int jl = 0; jl < 8; ++jl) tmp[jl] = (f16)tl[wgl * 8 + jl][c];
        *(f16x8*)&w0p[(size_t)(c0 + c) * 2048 + (wg0 + wgl) * 32 + jh * 8] =
            *(f16x8*)tmp;
    }
}

struct PArgs {
    const int* skills; const int* corrects;
    const f16* W0P;
    const f16* Whh0; const f16* Wih1; const f16* Whh1;
    const float* b0; const float* b1;
    f16* h1; f16* h2;
    u32* arrive;   // 256 flags, u32 stride 16
};

// ---- persistent MFMA 2-layer LSTM: 64 WGs (1/CU), per-WAVE flags, NO barriers ----
// WG owns units [wg*8, wg*8+8) of BOTH layers (32 gate rows/layer).
// Wave roles: w0 = L0/batches 0-31, w1 = L0/b 32-63, w2 = L1/b 0-31, w3 = L1/b 32-63.
// Each wave: full-K gates via 32 MFMAs/matrix (B frags VGPR-resident), i/f/g/o
// re-association via __shfl, cell on 16 lanes, h stored [t][b][u] f16 (sc1),
// per-wave flag after inline vmcnt(0). All waves poll 4 flags/lane.
__global__ __launch_bounds__(256, 1) void lstm_mfma(PArgs a) {
    const int wg   = blockIdx.x;
    const int tid  = threadIdx.x;
    const int lane = tid & 63;
    const int w    = tid >> 6;
    const int mi   = w & 1;                // batch half
    const bool isL1 = (w >= 2);
    const int u0   = wg * 8;
    const int n    = lane & 31;            // C col = gate*8 + unit_local
    const int nh   = lane >> 5;            // k-subchunk / C row-half
    const int rown = (n >> 3) * HID + u0 + (n & 7);   // weight row for col n
    const int brow = mi * 32 + n;          // A row = batch

    // ---- B fragments in VGPRs: B0 = (L0 ? Whh0 : Wih1), B1 = Whh1 (L1 only) ----
    const f16* Wb0 = isL1 ? a.Wih1 : a.Whh0;
    f16x8 B0[32], B1[32];
#pragma unroll
    for (int f = 0; f < 32; ++f)
        B0[f] = *(const f16x8*)(Wb0 + (size_t)rown * HID + f * 16 + nh * 8);
    if (isL1) {
#pragma unroll
        for (int f = 0; f < 32; ++f)
            B1[f] = *(const f16x8*)(a.Whh1 + (size_t)rown * HID + f * 16 + nh * 8);
    }
    const float biasv = (isL1 ? a.b1 : a.b0)[rown];

    float cst[16];
#pragma unroll
    for (int r = 0; r < 16; ++r) cst[r] = 0.0f;

    // x prefetch (L0 waves): xv[r] = f16 bits of W0P[idx(b(r),t)][wg][n]
    u16 xv[16];
#pragma unroll
    for (int r = 0; r < 16; ++r) xv[r] = 0;
    if (!isL1) {
#pragma unroll
        for (int r = 0; r < 16; ++r) {
            int b = mi * 32 + (r & 3) + 8 * (r >> 2) + 4 * nh;
            int sk = a.skills[b * SEQ + 0];
            int co = a.corrects[b * SEQ + 0];
            if (sk >= 0) {
                int idx = sk + NSK * ((co == 1) ? 0 : 1);
                xv[r] = *(const u16*)(a.W0P + (size_t)idx * 2048 + wg * 32 + n);
            }
        }
    }

    const int s8  = (lane & 32) | ((n + 8) & 31);
    const int s16 = (lane & 32) | ((n + 16) & 31);
    const int s24 = (lane & 32) | ((n + 24) & 31);

    for (int tau = 0; tau <= SEQ; ++tau) {
        const bool active = isL1 ? (tau >= 1) : (tau < SEQ);
        if (active) {
            const int t = isL1 ? tau - 1 : tau;

            f32x16 acc;
#pragma unroll
            for (int j = 0; j < 16; ++j) acc[j] = 0.0f;

            uint4 af[32];
            if (!isL1) {
                if (tau >= 1) {   // hh0 term: A = h1[tau-1]
                    const f16* hp = a.h1 + (size_t)(tau - 1) * HSTEP
                                  + (size_t)brow * HID + nh * 8;
#pragma unroll
                    for (int f = 0; f < 32; ++f) af[f] = *(const uint4*)(hp + f * 16);
#pragma unroll
                    for (int f = 0; f < 32; ++f)
                        acc = __builtin_amdgcn_mfma_f32_32x32x16_f16(
                            __builtin_bit_cast(f16x8, af[f]), B0[f], acc, 0, 0, 0);
                }
            } else {
                // ih1 term: A = h1[tau-1]
                const f16* hp1 = a.h1 + (size_t)(tau - 1) * HSTEP
                               + (size_t)brow * HID + nh * 8;
#pragma unroll
                for (int f = 0; f < 32; ++f) af[f] = *(const uint4*)(hp1 + f * 16);
#pragma unroll
                for (int f = 0; f < 32; ++f)
                    acc = __builtin_amdgcn_mfma_f32_32x32x16_f16(
                        __builtin_bit_cast(f16x8, af[f]), B0[f], acc, 0, 0, 0);
                if (tau >= 2) {   // hh1 term: A = h2[tau-2]
                    const f16* hp2 = a.h2 + (size_t)(tau - 2) * HSTEP
                                   + (size_t)brow * HID + nh * 8;
#pragma unroll
                    for (int f = 0; f < 32; ++f) af[f] = *(const uint4*)(hp2 + f * 16);
#pragma unroll
                    for (int f = 0; f < 32; ++f)
                        acc = __builtin_amdgcn_mfma_f32_32x32x16_f16(
                            __builtin_bit_cast(f16x8, af[f]), B1[f], acc, 0, 0, 0);
                }
            }

            // ---- pre-gate = acc + bias + x (all lanes), then shfl f/g/o in ----
            float pre[16];
#pragma unroll
            for (int r = 0; r < 16; ++r) {
                pre[r] = acc[r] + biasv;
                if (!isL1)
                    pre[r] += (float)__builtin_bit_cast(f16, xv[r]);
            }

            // ---- cell on lanes with n<8 (unit = u0+n); rows = 16 batches ----
            f16* hb = (isL1 ? a.h2 : a.h1) + (size_t)t * HSTEP + (u0 + n);
            const bool usec = isL1 ? (tau >= 2) : (tau >= 1);
#pragma unroll
            for (int r = 0; r < 16; ++r) {
                float pf = __shfl(pre[r], s8, 64);
                float pg = __shfl(pre[r], s16, 64);
                float po = __shfl(pre[r], s24, 64);
                if (n < 8) {
                    float c_ = usec ? cst[r] : 0.0f;
                    float cn = sigmoidf_(pf) * c_ + sigmoidf_(pre[r]) * tanhf_(pg);
                    float hv = sigmoidf_(po) * tanhf_(cn);
                    cst[r] = cn;
                    int b = mi * 32 + (r & 3) + 8 * (r >> 2) + 4 * nh;
                    __hip_atomic_store((u16*)(hb + (size_t)b * HID),
                                       __builtin_bit_cast(u16, (f16)hv),
                                       __ATOMIC_RELAXED, __HIP_MEMORY_SCOPE_AGENT);
                }
            }
        }

        if (tau < SEQ) {
            // ---- per-wave flag: own stores drained, then announce ----
            asm volatile("s_waitcnt vmcnt(0)" ::: "memory");
            if (lane == 0)
                __hip_atomic_store(&a.arrive[(wg * 4 + w) * 16], (u32)(tau + 1),
                                   __ATOMIC_RELAXED, __HIP_MEMORY_SCOPE_AGENT);

            // ---- x prefetch for t = tau+1 (hidden under the poll) ----
            if (!isL1 && tau + 1 < SEQ) {
#pragma unroll
                for (int r = 0; r < 16; ++r) {
                    int b = mi * 32 + (r & 3) + 8 * (r >> 2) + 4 * nh;
                    int sk = a.skills[b * SEQ + tau + 1];
                    int co = a.corrects[b * SEQ + tau + 1];
                    u16 v = 0;
                    if (sk >= 0) {
                        int idx = sk + NSK * ((co == 1) ? 0 : 1);
                        v = *(const u16*)(a.W0P + (size_t)idx * 2048 + wg * 32 + n);
                    }
                    xv[r] = v;
                }
            }

            // ---- poll all 256 wave-flags (4 per lane) ----
            const u32 want = (u32)(tau + 1);
            int guard = 0;
            while (true) {
                u32 v0 = __hip_atomic_load(&a.arrive[(lane) * 16],
                                           __ATOMIC_RELAXED, __HIP_MEMORY_SCOPE_AGENT);
                u32 v1 = __hip_atomic_load(&a.arrive[(lane + 64) * 16],
                                           __ATOMIC_RELAXED, __HIP_MEMORY_SCOPE_AGENT);
                u32 v2 = __hip_atomic_load(&a.arrive[(lane + 128) * 16],
                                           __ATOMIC_RELAXED, __HIP_MEMORY_SCOPE_AGENT);
                u32 v3 = __hip_atomic_load(&a.arrive[(lane + 192) * 16],
                                           __ATOMIC_RELAXED, __HIP_MEMORY_SCOPE_AGENT);
                u32 mn = min(min(v0, v1), min(v2, v3));
                if (__ballot(mn < want) == 0ull) break;
                __builtin_amdgcn_s_sleep(1);
                if (++guard > (1 << 20)) break;   // visible failure, never hang
            }
            // keep next tick's plain h-loads from hoisting above the poll
            asm volatile("" ::: "memory");
            __builtin_amdgcn_sched_barrier(0);
        }
    }
}

// ---- projection (MFMA): out[b][t][n] = sigmoid(h2[t][b][:] . fcW[n] + fcb[n])
// block = 4 timesteps x 64 cols; wave w = batches [w*16, w*16+16) over those 4 t.
__global__ __launch_bounds__(256) void proj_mfma(
    const f16* __restrict__ h2, const f16* __restrict__ fcwh,
    const float* __restrict__ fcb, float* __restrict__ out)
{
    const int tg = blockIdx.x >> 4;     // t-group (4 timesteps)
    const int nt = blockIdx.x & 15;     // 64-col group
    const int tid = threadIdx.x;
    const int l = tid & 63;
    const int w = tid >> 6;             // batch-tile
    const int col = l & 15;
    const int kb = l >> 4;

    f32x4 acc[4][4];                    // [t-local j][n-tile]
#pragma unroll
    for (int j = 0; j < 4; ++j)
#pragma unroll
        for (int v = 0; v < 4; ++v) acc[j][v] = (f32x4){0, 0, 0, 0};

    float fb[4];
#pragma unroll
    for (int v = 0; v < 4; ++v) fb[v] = fcb[nt * 64 + v * 16 + col];

#pragma unroll 2
    for (int f = 0; f < 16; ++f) {
        f16x8 Bf[4];
#pragma unroll
        for (int v = 0; v < 4; ++v) {
            int nn = nt * 64 + v * 16 + col;
            Bf[v] = *(const f16x8*)(fcwh + (size_t)nn * HID + f * 32 + kb * 8);
        }
#pragma unroll
        for (int j = 0; j < 4; ++j) {
            const f16* hp = h2 + (size_t)(tg * 4 + j) * HSTEP
                          + (size_t)(w * 16 + col) * HID + f * 32 + kb * 8;
            uint4 au = *(const uint4*)hp;
#pragma unroll
            for (int v = 0; v < 4; ++v)
                acc[j][v] = __builtin_amdgcn_mfma_f32_16x16x32_f16(
                    __builtin_bit_cast(f16x8, au), Bf[v], acc[j][v], 0, 0, 0);
        }
    }

    // epilogue: C layout col=lane&15, row=(lane>>4)*4+r
#pragma unroll
    for (int j = 0; j < 4; ++j) {
        int t = tg * 4 + j;
#pragma unroll
        for (int v = 0; v < 4; ++v) {
            int nn = nt * 64 + v * 16 + col;
#pragma unroll
            for (int r = 0; r < 4; ++r) {
                int b = w * 16 + kb * 4 + r;
                out[((size_t)b * SEQ + t) * NSK + nn] = sigmoidf_(acc[j][v][r] + fb[v]);
            }
        }
    }
}

extern "C" void kernel_launch(void* const* d_in, const int* in_sizes, int n_in,
                              void* d_out, int out_size, void* d_ws, size_t ws_size,
                              hipStream_t stream) {
    (void)in_sizes; (void)n_in; (void)out_size; (void)ws_size;

    const int*   skills   = (const int*)d_in[0];
    const int*   corrects = (const int*)d_in[1];
    const float* Wih0 = (const float*)d_in[2];
    const float* Whh0 = (const float*)d_in[3];
    const float* bih0 = (const float*)d_in[4];
    const float* bhh0 = (const float*)d_in[5];
    const float* Wih1 = (const float*)d_in[6];
    const float* Whh1 = (const float*)d_in[7];
    const float* bih1 = (const float*)d_in[8];
    const float* bhh1 = (const float*)d_in[9];
    const float* fcW  = (const float*)d_in[10];
    const float* fcb  = (const float*)d_in[11];

    char* ws = (char*)d_ws;
    f16*  h1    = (f16*)(ws + H1_OFF);
    f16*  h2    = (f16*)(ws + H2_OFF);
    f16*  whh0h = (f16*)(ws + WHH0_OFF);
    f16*  wih1h = (f16*)(ws + WIH1_OFF);
    f16*  whh1h = (f16*)(ws + WHH1_OFF);
    f16*  fcwh  = (f16*)(ws + FCW_OFF);
    float* b0   = (float*)(ws + B0_OFF);
    float* b1   = (float*)(ws + B1_OFF);
    f16*  w0p   = (f16*)(ws + W0P_OFF);
    u32*  flags = (u32*)(ws + FLG_OFF);

    prep_kernel<<<4096, 256, 0, stream>>>(Whh0, Wih1, Whh1, fcW, bih0, bhh0,
                                          bih1, bhh1, whh0h, wih1h, whh1h, fcwh,
                                          b0, b1, flags);
    w0p_kernel<<<1024, 256, 0, stream>>>(Wih0, w0p);

    PArgs pa;
    pa.skills = skills; pa.corrects = corrects; pa.W0P = w0p;
    pa.Whh0 = whh0h; pa.Wih1 = wih1h; pa.Whh1 = whh1h;
    pa.b0 = b0; pa.b1 = b1; pa.h1 = h1; pa.h2 = h2;
    pa.arrive = flags;

    lstm_mfma<<<NWG, 256, 0, stream>>>(pa);

    proj_mfma<<<2048, 256, 0, stream>>>(h2, fcwh, fcb, (float*)d_out);
}

// Round 7
// 4251.897 us; speedup vs baseline: 2.2258x; 2.2258x over previous
//
#include <hip/hip_runtime.h>
#include <hip/hip_fp16.h>

typedef _Float16 f16;
typedef unsigned int u32;
typedef unsigned long long u64;
typedef _Float16 f16x4 __attribute__((ext_vector_type(4)));
typedef _Float16 f16x8 __attribute__((ext_vector_type(8)));
typedef float f32x4 __attribute__((ext_vector_type(4)));
typedef float f32x16 __attribute__((ext_vector_type(16)));

#define SEQ   512
#define HID   512
#define NSK   1024
#define INDIM 2048
#define NWG   64
#define HSTEP 32768   // f16 per timestep, tiled layout [ug=u>>3][b][u&7]

// ---- workspace layout (bytes) ----
#define H1_OFF    0ull
#define H2_OFF    33554432ull
#define WHH0_OFF  67108864ull
#define WIH1_OFF  69206016ull
#define WHH1_OFF  71303168ull
#define FCW_OFF   73400320ull
#define BF_OFF    74448896ull   // bfold [2][64][32] f32 (16KB)
#define W0P_OFF   74465280ull   // 8 MB: [2048 col][64 wg][32 j] f16, j = gate*8+unit
#define FLG_OFF   82853888ull   // 64 per-WG flags, 64B apart (u32 stride 16)
#define SIDX_OFF  82857984ull   // [512 t][64 b] int combined gather index (128KB)

__device__ __forceinline__ float sigmoidf_(float x) {
    return 1.0f / (1.0f + __expf(-x));
}
__device__ __forceinline__ float tanhf_(float x) {
    return 2.0f * sigmoidf_(2.0f * x) - 1.0f;
}

// ---- prep: f16 weights, folded per-WG bias, transposed gather index, flags ----
__global__ __launch_bounds__(256) void prep_kernel(
    const int* __restrict__ skills, const int* __restrict__ corrects,
    const float* __restrict__ Whh0, const float* __restrict__ Wih1,
    const float* __restrict__ Whh1, const float* __restrict__ fcW,
    const float* __restrict__ bih0, const float* __restrict__ bhh0,
    const float* __restrict__ bih1, const float* __restrict__ bhh1,
    f16* __restrict__ whh0h, f16* __restrict__ wih1h,
    f16* __restrict__ whh1h, f16* __restrict__ fcwh,
    float* __restrict__ bfold, int* __restrict__ sidx, u32* __restrict__ flags)
{
    int i = blockIdx.x * 256 + threadIdx.x;
    if (i < 2048 * 512) {
        whh0h[i] = (f16)Whh0[i];
        wih1h[i] = (f16)Wih1[i];
        whh1h[i] = (f16)Whh1[i];
    }
    if (i < 1024 * 512) fcwh[i] = (f16)fcW[i];
    if (i < 4096) {
        int lyr = i >> 11, wgi = (i >> 5) & 63, j = i & 31;
        int row = ((j >> 3) << 9) + wgi * 8 + (j & 7);
        bfold[i] = lyr ? (bih1[row] + bhh1[row]) : (bih0[row] + bhh0[row]);
    }
    if (i < SEQ * 64) {
        int t = i >> 6, b = i & 63;
        int sk = skills[b * SEQ + t], co = corrects[b * SEQ + t];
        sidx[i] = (sk >= 0) ? (sk + NSK * ((co == 1) ? 0 : 1)) : -1;
    }
    if (i < 1024) flags[i] = 0;
}

// ---- W0P build: W0P[c][wg][j] = Wih0[r][c], r = (j>>3)*512 + wg*8 + (j&7) ----
__global__ __launch_bounds__(256) void w0p_kernel(
    const float* __restrict__ Wih0, f16* __restrict__ w0p)
{
    __shared__ float tl[64][65];
    const int tid = threadIdx.x;
    const int ct = blockIdx.x & 31, rt = blockIdx.x >> 5;
    const int r0 = rt * 64, c0 = ct * 64;
#pragma unroll 4
    for (int i = 0; i < 16; ++i) {
        int rr = i * 4 + (tid >> 6);
        int cc = tid & 63;
        tl[rr][cc] = Wih0[(size_t)(r0 + rr) * INDIM + c0 + cc];
    }
    __syncthreads();
    const int jh = r0 >> 9;            // gate (const in tile)
    const int wg0 = (r0 & 511) >> 3;   // first wg chunk
    for (int task = tid; task < 512; task += 256) {
        int c = task >> 3, wgl = task & 7;
        f16 tmp[8];
#pragma unroll
        for (int jl = 0; jl < 8; ++jl) tmp[jl] = (f16)tl[wgl * 8 + jl][c];
        *(f16x8*)&w0p[(size_t)(c0 + c) * 2048 + (wg0 + wgl) * 32 + jh * 8] =
            *(f16x8*)tmp;
    }
}

struct PArgs {
    const int* sidx; const f16* W0P;
    const f16* Whh0; const f16* Wih1; const f16* Whh1;
    const float* bfold;
    f16* h1; f16* h2;
    u32* flags;
};

// ---- persistent MFMA 2-layer LSTM: 64 WGs (1/CU), wave-autonomous ticks ----
// Operand-swapped MFMA: D = W(A) x h^T(B); D col = batch, rows = gate*8+unit.
// Waves: w0 = L0/b0-31, w1 = L1/b0-31, w2 = L1/b32-63, w3 = L0/b32-63.
// L0: Whh0 in VGPR (32 frags). L1: Wih1 in VGPR + Whh1 from swizzled LDS.
// Cell fully in-register (lane = batch col, gates in acc rows). No syncthreads,
// no LDS exchange in the loop. Per-wave LDS done flags -> w0 -> 1 global
// flag/WG (sc1); everyone polls 64 flags (1/lane). R2 lesson: NO fences.
__global__ __launch_bounds__(256, 1) void lstm_mfma(PArgs a) {
    __shared__ f16 wlds[32 * 64 * 8];   // 32KB: Whh1 rows for this WG, swizzled
    __shared__ u32 ldone[64];           // 4 used, stride 16

    const int wg   = blockIdx.x;
    const int tid  = threadIdx.x;
    const int lane = tid & 63;
    const int w    = tid >> 6;
    const bool isL1 = (w == 1 || w == 2);
    const int tl   = (w >= 2) ? 1 : 0;       // batch half
    const int n    = lane & 31;
    const int nh   = lane >> 5;
    const int b    = tl * 32 + n;            // batch (B col / cell lane)
    const int rown = ((n >> 3) << 9) + wg * 8 + (n & 7);   // weight row for A row n

    // stage Whh1 -> LDS (swizzled chunks: phys = ch ^ (row&7))
    for (int i = tid; i < 2048; i += 256) {
        int rn = i >> 6, ch = i & 63;
        int rr = ((rn >> 3) << 9) + wg * 8 + (rn & 7);
        *(uint4*)&wlds[(rn * 64 + (ch ^ (rn & 7))) * 8] =
            *(const uint4*)(a.Whh1 + (size_t)rr * HID + ch * 8);
    }
    if (tid < 4) ldone[tid * 16] = 0;

    // VGPR-resident weight frags (32 x f16x8 = 128 VGPR)
    const f16* WA = isL1 ? a.Wih1 : a.Whh0;
    f16x8 Wf[32];
#pragma unroll
    for (int f = 0; f < 32; ++f)
        Wf[f] = *(const f16x8*)(WA + (size_t)rown * HID + f * 16 + nh * 8);

    // bias: bf{g}[uu] for unit nh*4+uu, gate g
    float4 bf0, bf1, bf2, bf3;
    {
        const float* bp = a.bfold + (isL1 ? 2048 : 0) + wg * 32 + nh * 4;
        bf0 = *(const float4*)(bp + 0);
        bf1 = *(const float4*)(bp + 8);
        bf2 = *(const float4*)(bp + 16);
        bf3 = *(const float4*)(bp + 24);
    }

    float cst[4] = {0.0f, 0.0f, 0.0f, 0.0f};

    // L0 x-gather prefetch for t=0
    int sid = -1;
    uint2 xq0 = {0, 0}, xq1 = {0, 0}, xq2 = {0, 0}, xq3 = {0, 0};
    if (!isL1) {
        sid = a.sidx[b];
        if (sid >= 0) {
            const char* xp = (const char*)a.W0P + (size_t)sid * 4096 + wg * 64 + nh * 8;
            xq0 = *(const uint2*)(xp);
            xq1 = *(const uint2*)(xp + 16);
            xq2 = *(const uint2*)(xp + 32);
            xq3 = *(const uint2*)(xp + 48);
        }
    }

    __syncthreads();   // staging + flag init done (only pre-loop barrier)

    for (int tau = 0; tau <= SEQ; ++tau) {
        const bool active = isL1 ? (tau >= 1) : (tau < SEQ);
        if (active) {
            const int t = isL1 ? tau - 1 : tau;
            f32x16 acc;
#pragma unroll
            for (int j = 0; j < 16; ++j) acc[j] = 0.0f;

            if (tau >= 1) {
                // term with A-weights in VGPR, B = h1[tau-1]
                const f16* hb1 = a.h1 + (size_t)(tau - 1) * HSTEP;
                uint4 Bh[32];
#pragma unroll
                for (int f = 0; f < 32; ++f)
                    Bh[f] = *(const uint4*)(hb1 + ((f * 2 + nh) * 64 + b) * 8);
#pragma unroll
                for (int f = 0; f < 32; ++f)
                    acc = __builtin_amdgcn_mfma_f32_32x32x16_f16(
                        Wf[f], __builtin_bit_cast(f16x8, Bh[f]), acc, 0, 0, 0);
                if (isL1 && tau >= 2) {
                    // hh1 term: A = Whh1 from LDS, B = h2[tau-2]
                    const f16* hb2 = a.h2 + (size_t)(tau - 2) * HSTEP;
#pragma unroll
                    for (int f = 0; f < 32; ++f)
                        Bh[f] = *(const uint4*)(hb2 + ((f * 2 + nh) * 64 + b) * 8);
#pragma unroll
                    for (int f = 0; f < 32; ++f) {
                        f16x8 Af = *(const f16x8*)
                            &wlds[(n * 64 + ((f * 2 + nh) ^ (n & 7))) * 8];
                        acc = __builtin_amdgcn_mfma_f32_32x32x16_f16(
                            Af, __builtin_bit_cast(f16x8, Bh[f]), acc, 0, 0, 0);
                    }
                }
            }

            // ---- cell, fully in-register: lane = batch b, units nh*4+uu ----
            const bool usec = isL1 ? (tau >= 2) : (tau >= 1);
            f16x4 x0 = __builtin_bit_cast(f16x4, xq0);
            f16x4 x1 = __builtin_bit_cast(f16x4, xq1);
            f16x4 x2 = __builtin_bit_cast(f16x4, xq2);
            f16x4 x3 = __builtin_bit_cast(f16x4, xq3);
            f16 hh[4];
#pragma unroll
            for (int uu = 0; uu < 4; ++uu) {
                float gi = acc[uu]      + bf0[uu] + (float)x0[uu];
                float gf = acc[4 + uu]  + bf1[uu] + (float)x1[uu];
                float gg = acc[8 + uu]  + bf2[uu] + (float)x2[uu];
                float go = acc[12 + uu] + bf3[uu] + (float)x3[uu];
                float c_ = usec ? cst[uu] : 0.0f;
                float cn = sigmoidf_(gf) * c_ + sigmoidf_(gi) * tanhf_(gg);
                float hv = sigmoidf_(go) * tanhf_(cn);
                cst[uu] = cn;
                hh[uu] = (f16)hv;
            }
            union { f16x4 h; u64 d; } hp;
            hp.h = (f16x4){hh[0], hh[1], hh[2], hh[3]};
            f16* hbase = isL1 ? a.h2 : a.h1;
            u64* dst = (u64*)(hbase + (size_t)t * HSTEP + ((wg * 64 + b) * 8 + nh * 4));
            __hip_atomic_store(dst, hp.d, __ATOMIC_RELAXED, __HIP_MEMORY_SCOPE_AGENT);
        }

        if (tau < SEQ) {
            // own stores drained -> wave-done (LDS) -> w0 aggregates -> WG flag
            asm volatile("s_waitcnt vmcnt(0)" ::: "memory");
            if (lane == 0)
                __hip_atomic_store(&ldone[w * 16], (u32)(tau + 1),
                                   __ATOMIC_RELAXED, __HIP_MEMORY_SCOPE_WORKGROUP);
            if (w == 0) {
                const u32 wantl = (u32)(tau + 1);
                int g2 = 0;
                while (true) {
                    u32 v = __hip_atomic_load(&ldone[(lane & 3) * 16],
                                              __ATOMIC_RELAXED, __HIP_MEMORY_SCOPE_WORKGROUP);
                    if (__ballot(v < wantl) == 0ull) break;
                    if (++g2 > (1 << 22)) break;    // visible failure, never hang
                }
                if (lane == 0)
                    __hip_atomic_store(&a.flags[wg * 16], (u32)(tau + 1),
                                       __ATOMIC_RELAXED, __HIP_MEMORY_SCOPE_AGENT);
            }

            // x-gather prefetch for tick tau+1 (hidden under the poll)
            if (!isL1 && tau + 1 < SEQ) {
                sid = a.sidx[(tau + 1) * 64 + b];
                if (sid >= 0) {
                    const char* xp = (const char*)a.W0P + (size_t)sid * 4096 + wg * 64 + nh * 8;
                    xq0 = *(const uint2*)(xp);
                    xq1 = *(const uint2*)(xp + 16);
                    xq2 = *(const uint2*)(xp + 32);
                    xq3 = *(const uint2*)(xp + 48);
                } else {
                    xq0 = xq1 = xq2 = xq3 = (uint2){0, 0};
                }
            }

            // global poll: 64 WG-flags, one per lane
            const u32 want = (u32)(tau + 1);
            int guard = 0;
            while (true) {
                u32 v = __hip_atomic_load(&a.flags[lane * 16],
                                          __ATOMIC_RELAXED, __HIP_MEMORY_SCOPE_AGENT);
                if (__ballot(v < want) == 0ull) break;
                __builtin_amdgcn_s_sleep(1);
                if (++guard > (1 << 20)) break;     // visible failure, never hang
            }
            // keep next tick's plain h-loads from hoisting above the poll
            asm volatile("" ::: "memory");
            __builtin_amdgcn_sched_barrier(0);
        }
    }
}

// ---- projection (MFMA): out[b][t][n] = sigmoid(h2[t][b][:] . fcW[n] + fcb[n])
// h2 tiled layout [t][ug][b][8]. block = 4 timesteps x 64 cols; wave = 16 batches.
__global__ __launch_bounds__(256) void proj_mfma(
    const f16* __restrict__ h2, const f16* __restrict__ fcwh,
    const float* __restrict__ fcb, float* __restrict__ out)
{
    const int tg = blockIdx.x >> 4;     // t-group (4 timesteps)
    const int nt = blockIdx.x & 15;     // 64-col group
    const int tid = threadIdx.x;
    const int l = tid & 63;
    const int w = tid >> 6;             // batch-tile
    const int col = l & 15;
    const int kb = l >> 4;

    f32x4 acc[4][4];
#pragma unroll
    for (int j = 0; j < 4; ++j)
#pragma unroll
        for (int v = 0; v < 4; ++v) acc[j][v] = (f32x4){0, 0, 0, 0};

    float fb[4];
#pragma unroll
    for (int v = 0; v < 4; ++v) fb[v] = fcb[nt * 64 + v * 16 + col];

#pragma unroll 2
    for (int f = 0; f < 16; ++f) {
        f16x8 Bf[4];
#pragma unroll
        for (int v = 0; v < 4; ++v) {
            int nn = nt * 64 + v * 16 + col;
            Bf[v] = *(const f16x8*)(fcwh + (size_t)nn * HID + f * 32 + kb * 8);
        }
#pragma unroll
        for (int j = 0; j < 4; ++j) {
            const f16* hp = h2 + (size_t)(tg * 4 + j) * HSTEP
                          + ((f * 4 + kb) * 64 + (w * 16 + col)) * 8;
            uint4 au = *(const uint4*)hp;
#pragma unroll
            for (int v = 0; v < 4; ++v)
                acc[j][v] = __builtin_amdgcn_mfma_f32_16x16x32_f16(
                    __builtin_bit_cast(f16x8, au), Bf[v], acc[j][v], 0, 0, 0);
        }
    }

    // epilogue: C layout col=lane&15, row=(lane>>4)*4+r
#pragma unroll
    for (int j = 0; j < 4; ++j) {
        int t = tg * 4 + j;
#pragma unroll
        for (int v = 0; v < 4; ++v) {
            int nn = nt * 64 + v * 16 + col;
#pragma unroll
            for (int r = 0; r < 4; ++r) {
                int b = w * 16 + kb * 4 + r;
                out[((size_t)b * SEQ + t) * NSK + nn] = sigmoidf_(acc[j][v][r] + fb[v]);
            }
        }
    }
}

extern "C" void kernel_launch(void* const* d_in, const int* in_sizes, int n_in,
                              void* d_out, int out_size, void* d_ws, size_t ws_size,
                              hipStream_t stream) {
    (void)in_sizes; (void)n_in; (void)out_size; (void)ws_size;

    const int*   skills   = (const int*)d_in[0];
    const int*   corrects = (const int*)d_in[1];
    const float* Wih0 = (const float*)d_in[2];
    const float* Whh0 = (const float*)d_in[3];
    const float* bih0 = (const float*)d_in[4];
    const float* bhh0 = (const float*)d_in[5];
    const float* Wih1 = (const float*)d_in[6];
    const float* Whh1 = (const float*)d_in[7];
    const float* bih1 = (const float*)d_in[8];
    const float* bhh1 = (const float*)d_in[9];
    const float* fcW  = (const float*)d_in[10];
    const float* fcb  = (const float*)d_in[11];

    char* ws = (char*)d_ws;
    f16*  h1    = (f16*)(ws + H1_OFF);
    f16*  h2    = (f16*)(ws + H2_OFF);
    f16*  whh0h = (f16*)(ws + WHH0_OFF);
    f16*  wih1h = (f16*)(ws + WIH1_OFF);
    f16*  whh1h = (f16*)(ws + WHH1_OFF);
    f16*  fcwh  = (f16*)(ws + FCW_OFF);
    float* bfold = (float*)(ws + BF_OFF);
    f16*  w0p   = (f16*)(ws + W0P_OFF);
    u32*  flags = (u32*)(ws + FLG_OFF);
    int*  sidx  = (int*)(ws + SIDX_OFF);

    prep_kernel<<<4096, 256, 0, stream>>>(skills, corrects, Whh0, Wih1, Whh1, fcW,
                                          bih0, bhh0, bih1, bhh1,
                                          whh0h, wih1h, whh1h, fcwh,
                                          bfold, sidx, flags);
    w0p_kernel<<<1024, 256, 0, stream>>>(Wih0, w0p);

    PArgs pa;
    pa.sidx = sidx; pa.W0P = w0p;
    pa.Whh0 = whh0h; pa.Wih1 = wih1h; pa.Whh1 = whh1h;
    pa.bfold = bfold; pa.h1 = h1; pa.h2 = h2;
    pa.flags = flags;

    lstm_mfma<<<NWG, 256, 0, stream>>>(pa);

    proj_mfma<<<2048, 256, 0, stream>>>(h2, fcwh, fcb, (float*)d_out);
}